// Round 1
// 379.599 us; speedup vs baseline: 1.4231x; 1.4231x over previous
//
#include <hip/hip_runtime.h>

// CRF log-likelihood: B=256, S=2048, L=64, START=62, END=63.
//
// NEW STRUCTURE (this round): chunked linear-operator scan on matrix cores.
// The recurrence E_{s+1} = diag(l_s)*P*E_s is a chain of linear maps.
// 8 chunks x 256 steps: wave (b,c) computes G_c = prod of its 256 matrices
// via v_mfma_f32_32x32x16_f16 (16 MFMA / step = exact 64x64x64 matmul).
// 2048 waves (2/SIMD) replaces 256 waves (0.25/SIMD) -> latency hidden.
// A combine kernel does E = G_7*...*G_0*e_START (8 f32 matvecs) + gold + LSE.
//
// Layout-robustness trick: HW A-slot->k and B-slot->k maps are identical
// (symmetric fragments), so ANY self-consistent k-permutation cancels in the
// contraction. We choose k_my(hi,f) = 4*hi + (f&3) + 8*(f>>2) so that the
// acc(C-layout, HW-verified: col=lane&31,row=(r&3)+8*(r>>2)+4*hi) -> next-B
// conversion is ENTIRELY in-lane: just 32 v_cvt_pkrtz, no cross-lane ops.
// A (= exp(T) row-scaled by l*2^-c) and the G=I init use the same k_my.
//
// Renorm: power-of-2 proxy (max of acc tile00, readfirstlane of lane0=col0),
// lag-folded into next step's exp2 arg (lv = exp2(lg*L2E - c)); exact log2
// bookkeeping in int D. f16 headroom analysis: steady-state acc ~2^0, B
// entries ~2^3, >20 binades preserved above flush (current kernel: ~14).

#define Bsz 256
#define Ssz 2048
#define START_ 62
#define END_ 63
#define PSTRIDE 36   // old fallback kernel
#define CH 256       // steps per chunk
#define NC 8         // chunks per batch

typedef __attribute__((ext_vector_type(2))) _Float16 half2v;
typedef __attribute__((ext_vector_type(8))) _Float16 half8;
typedef __attribute__((ext_vector_type(16))) float f32x16;

__device__ __forceinline__ unsigned pack_pkrtz(float a, float b) {
    auto h = __builtin_amdgcn_cvt_pkrtz(a, b);   // __fp16 ext_vector(2)
    return __builtin_bit_cast(unsigned, h);
}

__device__ __forceinline__ float dot2h(unsigned a, unsigned b, float c) {
#if __has_builtin(__builtin_amdgcn_fdot2)
    return __builtin_amdgcn_fdot2(__builtin_bit_cast(half2v, a),
                                  __builtin_bit_cast(half2v, b), c, false);
#else
    half2v ha = __builtin_bit_cast(half2v, a);
    half2v hb = __builtin_bit_cast(half2v, b);
    c = __builtin_fmaf((float)ha.x, (float)hb.x, c);
    return __builtin_fmaf((float)ha.y, (float)hb.y, c);
#endif
}

__device__ __forceinline__ float wave_sum(float v) {
#pragma unroll
    for (int m = 32; m >= 1; m >>= 1) v += __shfl_xor(v, m, 64);
    return v;
}

// ---------------------------------------------------------------------------
// OLD serial kernel (kept verbatim as fallback when workspace is too small).
// ---------------------------------------------------------------------------
#define CRF_STEP(LG)                                                           \
    {                                                                          \
        const float l_ = __builtin_amdgcn_exp2f((LG) * L2E);                   \
        const int nbi_ = __builtin_amdgcn_update_dpp(                          \
            0, __float_as_int(E), 0xB1, 0xf, 0xf, true); /* quad_perm 1,0,3,2*/\
        const unsigned packed_ = pack_pkrtz(E, __int_as_float(nbi_));          \
        float c0 = 0.f, c1 = 0.f, c2 = 0.f, c3 = 0.f;                          \
        float c4 = 0.f, c5 = 0.f, c6 = 0.f, c7 = 0.f;                          \
        _Pragma("unroll")                                                      \
        for (int k8 = 0; k8 < 8; ++k8) {                                       \
            const uint4 q_ = q[k8];                                            \
            const unsigned t0 = (unsigned)__builtin_amdgcn_readlane(           \
                (int)packed_, 8 * k8 + 0);                                     \
            const unsigned t1 = (unsigned)__builtin_amdgcn_readlane(           \
                (int)packed_, 8 * k8 + 2);                                     \
            const unsigned t2 = (unsigned)__builtin_amdgcn_readlane(           \
                (int)packed_, 8 * k8 + 4);                                     \
            const unsigned t3 = (unsigned)__builtin_amdgcn_readlane(           \
                (int)packed_, 8 * k8 + 6);                                     \
            if (k8 & 1) {                                                      \
                c4 = dot2h(t0, q_.x, c4);                                      \
                c5 = dot2h(t1, q_.y, c5);                                      \
                c6 = dot2h(t2, q_.z, c6);                                      \
                c7 = dot2h(t3, q_.w, c7);                                      \
            } else {                                                           \
                c0 = dot2h(t0, q_.x, c0);                                      \
                c1 = dot2h(t1, q_.y, c1);                                      \
                c2 = dot2h(t2, q_.z, c2);                                      \
                c3 = dot2h(t3, q_.w, c3);                                      \
            }                                                                  \
        }                                                                      \
        const float y_ = ((c0 + c1) + (c2 + c3)) + ((c4 + c5) + (c6 + c7));    \
        const float Ey_ = y_ * l_;                                             \
        const int pb_ = __builtin_amdgcn_readlane(__float_as_int(Ey_), 0);     \
        const int ee_ = (pb_ >> 23) & 0xff;                                    \
        const float sc_ = __int_as_float((244 - ee_) << 23);                   \
        E = Ey_ * sc_;                                                         \
        D += ee_ - 117;                                                        \
    }

#define LOAD_QBLOCK()                                                          \
    {                                                                          \
        unsigned off_ = (unsigned)(lane * (PSTRIDE * 4));                      \
        asm volatile("" : "+v"(off_));                                         \
        const uint4* prow_ = (const uint4*)((const char*)Psh + off_);          \
        _Pragma("unroll")                                                      \
        for (int k8 = 0; k8 < 8; ++k8) q[k8] = prow_[k8];                      \
    }

__global__ __launch_bounds__(64)
__attribute__((amdgpu_waves_per_eu(1, 1)))
void crf_kernel(const float* __restrict__ logits,
                const float* __restrict__ transition,
                const int* __restrict__ labels,
                const int* __restrict__ lens,
                float* __restrict__ out)
{
    const int b    = blockIdx.x;
    const int lane = threadIdx.x;
    const float L2E = 1.4426950408889634f;
    const float LN2 = 0.6931471805599453f;

    __shared__ unsigned Psh[64 * PSTRIDE];

    const int len = lens[b];
    const float* lrow = logits + (size_t)b * (Ssz * 64);

#pragma unroll
    for (int k = 0; k < 32; ++k) {
        float p0 = __builtin_amdgcn_exp2f(transition[lane * 64 + 2 * k]     * L2E);
        float p1 = __builtin_amdgcn_exp2f(transition[lane * 64 + 2 * k + 1] * L2E);
        Psh[lane * PSTRIDE + k] = pack_pkrtz(p0, p1);
    }
    asm volatile("s_waitcnt lgkmcnt(0)" ::: "memory");

    float E = (lane == START_) ? 1.0f : 0.0f;
    int   D = 0;

    float lgb[8];
#pragma unroll
    for (int d = 0; d < 8; ++d) {
        int s0 = (d < len) ? d : (len - 1);
        lgb[d] = lrow[s0 * 64 + lane];
    }

    uint4 q[8];
    const int len8 = len & ~7;
    for (int s = 0; s < len8; s += 8) {
        LOAD_QBLOCK();
#pragma unroll
        for (int d = 0; d < 8; ++d) {
            const float lg = lgb[d];
            int pf = s + 8 + d;
            pf = (pf < len) ? pf : (len - 1);
            lgb[d] = lrow[pf * 64 + lane];
            CRF_STEP(lg);
        }
    }
    const int rem = len - len8;
    if (rem) {
        LOAD_QBLOCK();
        for (int d = 0; d < rem; ++d) {
            const float lg = lgb[d];
            CRF_STEP(lg);
        }
    }

    const float Pend = __builtin_amdgcn_exp2f(transition[END_ * 64 + lane] * L2E);
    const float tot  = wave_sum(E * Pend);
    const float norm = LN2 * ((float)D + __builtin_amdgcn_logf(tot));

    const int* lab = labels + (size_t)b * Ssz;
    float g = 0.0f;
    for (int s = lane; s < len; s += 64) {
        const int l1 = lab[s];
        const int l0 = (s == 0) ? START_ : lab[s - 1];
        g += lrow[s * 64 + l1] + transition[l1 * 64 + l0];
    }
    if (lane == 0) g += transition[END_ * 64 + lab[len - 1]];
    const float gold = wave_sum(g);

    if (lane == 0) out[b] = gold - norm;
}

// ---------------------------------------------------------------------------
// NEW: chunked matrix-scan kernels.
// ---------------------------------------------------------------------------

#define MF16(Aop, Bop, Cop) \
    __builtin_amdgcn_mfma_f32_32x32x16_f16((Aop), (Bop), (Cop), 0, 0, 0)

// One step-matmul: acc = (diag(l*2^-ci)*P) * G.  Uses PF, Bf, Z, ci, D, L2E.
#define STEP_COMPUTE(LGA, LGB)                                                 \
    f32x16 a00, a01, a10, a11;                                                 \
    {                                                                          \
        const float ncf_ = -(float)ci;                                         \
        const float lv0_ = __builtin_amdgcn_exp2f(                             \
            __builtin_fmaf((LGA), L2E, ncf_));                                 \
        const float lv1_ = __builtin_amdgcn_exp2f(                             \
            __builtin_fmaf((LGB), L2E, ncf_));                                 \
        D += ci;                                                               \
        const _Float16 h0_ = (_Float16)lv0_;                                   \
        const _Float16 h1_ = (_Float16)lv1_;                                   \
        const half8 sv0_ = {h0_, h0_, h0_, h0_, h0_, h0_, h0_, h0_};           \
        const half8 sv1_ = {h1_, h1_, h1_, h1_, h1_, h1_, h1_, h1_};           \
        half8 A_;                                                              \
        A_ = __builtin_bit_cast(half8, PF[0][0]) * sv0_;                       \
        a00 = MF16(A_, __builtin_bit_cast(half8, Bf[0][0]), Z);                \
        a01 = MF16(A_, __builtin_bit_cast(half8, Bf[0][1]), Z);                \
        A_ = __builtin_bit_cast(half8, PF[0][1]) * sv0_;                       \
        a00 = MF16(A_, __builtin_bit_cast(half8, Bf[1][0]), a00);              \
        a01 = MF16(A_, __builtin_bit_cast(half8, Bf[1][1]), a01);              \
        A_ = __builtin_bit_cast(half8, PF[0][2]) * sv0_;                       \
        a00 = MF16(A_, __builtin_bit_cast(half8, Bf[2][0]), a00);              \
        a01 = MF16(A_, __builtin_bit_cast(half8, Bf[2][1]), a01);              \
        A_ = __builtin_bit_cast(half8, PF[0][3]) * sv0_;                       \
        a00 = MF16(A_, __builtin_bit_cast(half8, Bf[3][0]), a00);              \
        a01 = MF16(A_, __builtin_bit_cast(half8, Bf[3][1]), a01);              \
        A_ = __builtin_bit_cast(half8, PF[1][0]) * sv1_;                       \
        a10 = MF16(A_, __builtin_bit_cast(half8, Bf[0][0]), Z);                \
        a11 = MF16(A_, __builtin_bit_cast(half8, Bf[0][1]), Z);                \
        A_ = __builtin_bit_cast(half8, PF[1][1]) * sv1_;                       \
        a10 = MF16(A_, __builtin_bit_cast(half8, Bf[1][0]), a10);              \
        a11 = MF16(A_, __builtin_bit_cast(half8, Bf[1][1]), a11);              \
        A_ = __builtin_bit_cast(half8, PF[1][2]) * sv1_;                       \
        a10 = MF16(A_, __builtin_bit_cast(half8, Bf[2][0]), a10);              \
        a11 = MF16(A_, __builtin_bit_cast(half8, Bf[2][1]), a11);              \
        A_ = __builtin_bit_cast(half8, PF[1][3]) * sv1_;                       \
        a10 = MF16(A_, __builtin_bit_cast(half8, Bf[3][0]), a10);              \
        a11 = MF16(A_, __builtin_bit_cast(half8, Bf[3][1]), a11);              \
        const float mxa_ = fmaxf(fmaxf(fmaxf(a00[0], a00[1]),                  \
                                       fmaxf(a00[2], a00[3])),                 \
                                 fmaxf(fmaxf(a00[4], a00[5]),                  \
                                       fmaxf(a00[6], a00[7])));                \
        const float mxb_ = fmaxf(fmaxf(fmaxf(a00[8], a00[9]),                  \
                                       fmaxf(a00[10], a00[11])),               \
                                 fmaxf(fmaxf(a00[12], a00[13]),                \
                                       fmaxf(a00[14], a00[15])));              \
        const int mb_ = __builtin_amdgcn_readfirstlane(                        \
            __float_as_int(fmaxf(mxa_, mxb_)));                                \
        ci = ((mb_ >> 23) & 0xff) - 121; /* drive next acc toward 2^-6 */      \
    }

// acc (C layout) -> B fragments, entirely in-lane thanks to k_my choice.
// BD0 covers tile rows 0..15 (k_my kb*16+4hi+{0,1,2,3,8,9,10,11}),
// BD1 covers tile rows 16..31.
#define TILE_TO_FRAGS(ACC, BD0, BD1)                                           \
    {                                                                          \
        (BD0) = make_uint4(pack_pkrtz(ACC[0], ACC[1]),                         \
                           pack_pkrtz(ACC[2], ACC[3]),                         \
                           pack_pkrtz(ACC[4], ACC[5]),                         \
                           pack_pkrtz(ACC[6], ACC[7]));                        \
        (BD1) = make_uint4(pack_pkrtz(ACC[8], ACC[9]),                         \
                           pack_pkrtz(ACC[10], ACC[11]),                       \
                           pack_pkrtz(ACC[12], ACC[13]),                       \
                           pack_pkrtz(ACC[14], ACC[15]));                      \
    }

#define STEP_FULL(LGA, LGB)                                                    \
    {                                                                          \
        STEP_COMPUTE(LGA, LGB);                                                \
        TILE_TO_FRAGS(a00, Bf[0][0], Bf[1][0]);                                \
        TILE_TO_FRAGS(a01, Bf[0][1], Bf[1][1]);                                \
        TILE_TO_FRAGS(a10, Bf[2][0], Bf[3][0]);                                \
        TILE_TO_FRAGS(a11, Bf[2][1], Bf[3][1]);                                \
    }

// Final step of the chunk: store raw acc (stored-G convention, true = G*2^D)
// row-major f32 using the HW-verified C layout. Coalesced 2x128B per store.
#define STEP_LAST(LGA, LGB)                                                    \
    {                                                                          \
        STEP_COMPUTE(LGA, LGB);                                                \
        float* gout_ = Gws + (size_t)bc * 4096;                                \
        _Pragma("unroll")                                                      \
        for (int r = 0; r < 16; ++r) {                                         \
            const int row0_ = (r & 3) + 8 * (r >> 2) + 4 * hi;                 \
            gout_[row0_ * 64 + lo5]             = a00[r];                      \
            gout_[row0_ * 64 + 32 + lo5]        = a01[r];                      \
            gout_[(row0_ + 32) * 64 + lo5]      = a10[r];                      \
            gout_[(row0_ + 32) * 64 + 32 + lo5] = a11[r];                      \
        }                                                                      \
        if (lane == 0) Dws[bc] = D;                                            \
    }

__global__ __launch_bounds__(64)
__attribute__((amdgpu_waves_per_eu(2, 2)))
void crf_chunk(const float* __restrict__ logits,
               const float* __restrict__ transition,
               const int* __restrict__ lens,
               float* __restrict__ Gws,
               int* __restrict__ Dws)
{
    const int bc   = blockIdx.x;
    const int b    = bc >> 3;
    const int c    = bc & 7;
    const int lane = threadIdx.x;
    const int lo5  = lane & 31;
    const int hi   = lane >> 5;
    const float L2E = 1.4426950408889634f;

    const int len = lens[b];
    const int s0  = c * CH;
    if (s0 >= len) {                       // identity chunk: combine skips it
        if (lane == 0) Dws[bc] = 0;
        return;
    }
    const int s1 = (s0 + CH < len) ? (s0 + CH) : len;

    // P fragments (A operand), k_my(hi,f) = 4*hi + (f&3) + 8*(f>>2):
    // PF[m][kb] halves f=0..7 hold exp(T[m*32+lo5][kb*16 + k_my]).
    uint4 PF[2][4];
#pragma unroll
    for (int m = 0; m < 2; ++m) {
#pragma unroll
        for (int kb = 0; kb < 4; ++kb) {
            const float* tp = transition + (m * 32 + lo5) * 64 + kb * 16 + 4 * hi;
            const float e0 = __builtin_amdgcn_exp2f(tp[0] * L2E);
            const float e1 = __builtin_amdgcn_exp2f(tp[1] * L2E);
            const float e2 = __builtin_amdgcn_exp2f(tp[2] * L2E);
            const float e3 = __builtin_amdgcn_exp2f(tp[3] * L2E);
            const float e4 = __builtin_amdgcn_exp2f(tp[8] * L2E);
            const float e5 = __builtin_amdgcn_exp2f(tp[9] * L2E);
            const float e6 = __builtin_amdgcn_exp2f(tp[10] * L2E);
            const float e7 = __builtin_amdgcn_exp2f(tp[11] * L2E);
            PF[m][kb] = make_uint4(pack_pkrtz(e0, e1), pack_pkrtz(e2, e3),
                                   pack_pkrtz(e4, e5), pack_pkrtz(e6, e7));
        }
    }

    // B fragments = G, initialized to identity (same k_my convention).
    uint4 Bf[4][2];
#pragma unroll
    for (int kb = 0; kb < 4; ++kb) {
#pragma unroll
        for (int nb = 0; nb < 2; ++nb) {
            const int col = nb * 32 + lo5;
            unsigned dw[4];
#pragma unroll
            for (int j = 0; j < 4; ++j) {
                const int k0 = kb * 16 + 4 * hi + (j >> 1) * 8 + (j & 1) * 2;
                const unsigned lo16 = (k0     == col) ? 0x3C00u : 0u;
                const unsigned hi16 = (k0 + 1 == col) ? 0x3C00u : 0u;
                dw[j] = lo16 | (hi16 << 16);
            }
            Bf[kb][nb] = make_uint4(dw[0], dw[1], dw[2], dw[3]);
        }
    }

    // Opaque zero accumulator seed (prevents per-step v_mov remat of 16 zeros).
    float z0 = 0.0f;
    asm volatile("" : "+v"(z0));
    f32x16 Z;
#pragma unroll
    for (int i = 0; i < 16; ++i) Z[i] = z0;

    int D  = 0;   // exact log2 of removed scale (wave-uniform)
    int ci = 0;   // scale used for the NEXT step (lag-folded renorm)

    const float* lrow = logits + (size_t)b * (Ssz * 64);
#define CLMP(x) (((x) < s1) ? (x) : (s1 - 1))

    // Rolling 4-deep logit prefetch: lanes 0-31 and 32-63 read rows lo5 and
    // 32+lo5 of step s (2 x 128B coalesced per step, both halves identical).
    float pA0, pA1, pA2, pA3, pB0, pB1, pB2, pB3;
    {
        int sI;
        sI = CLMP(s0 + 0); pA0 = lrow[sI * 64 + lo5]; pB0 = lrow[sI * 64 + 32 + lo5];
        sI = CLMP(s0 + 1); pA1 = lrow[sI * 64 + lo5]; pB1 = lrow[sI * 64 + 32 + lo5];
        sI = CLMP(s0 + 2); pA2 = lrow[sI * 64 + lo5]; pB2 = lrow[sI * 64 + 32 + lo5];
        sI = CLMP(s0 + 3); pA3 = lrow[sI * 64 + lo5]; pB3 = lrow[sI * 64 + 32 + lo5];
    }

    const int nfull = (s1 - s0) - 1;       // steps with B-frag update
    int t = 0;
    for (; t + 4 <= nfull; t += 4) {
        const int sp = s0 + t + 4;
        const int q0i = CLMP(sp), q1i = CLMP(sp + 1), q2i = CLMP(sp + 2), q3i = CLMP(sp + 3);
        const float nA0 = lrow[q0i * 64 + lo5], nB0 = lrow[q0i * 64 + 32 + lo5];
        const float nA1 = lrow[q1i * 64 + lo5], nB1 = lrow[q1i * 64 + 32 + lo5];
        const float nA2 = lrow[q2i * 64 + lo5], nB2 = lrow[q2i * 64 + 32 + lo5];
        const float nA3 = lrow[q3i * 64 + lo5], nB3 = lrow[q3i * 64 + 32 + lo5];
        STEP_FULL(pA0, pB0);
        STEP_FULL(pA1, pB1);
        STEP_FULL(pA2, pB2);
        STEP_FULL(pA3, pB3);
        pA0 = nA0; pB0 = nB0; pA1 = nA1; pB1 = nB1;
        pA2 = nA2; pB2 = nB2; pA3 = nA3; pB3 = nB3;
    }
    const int r_ = nfull - t;              // 0..3 remaining full steps
    if (r_ >= 1) STEP_FULL(pA0, pB0);
    if (r_ >= 2) STEP_FULL(pA1, pB1);
    if (r_ >= 3) STEP_FULL(pA2, pB2);

    float fA = pA0, fB = pB0;
    if (r_ == 1) { fA = pA1; fB = pB1; }
    else if (r_ == 2) { fA = pA2; fB = pB2; }
    else if (r_ == 3) { fA = pA3; fB = pB3; }
    STEP_LAST(fA, fB);
#undef CLMP
}

__global__ __launch_bounds__(64)
__attribute__((amdgpu_waves_per_eu(1, 1)))
void crf_combine(const float* __restrict__ logits,
                 const float* __restrict__ transition,
                 const int* __restrict__ labels,
                 const int* __restrict__ lens,
                 const float* __restrict__ Gws,
                 const int* __restrict__ Dws,
                 float* __restrict__ out)
{
    const int b    = blockIdx.x;
    const int lane = threadIdx.x;
    const float L2E = 1.4426950408889634f;
    const float LN2 = 0.6931471805599453f;
    const int len = lens[b];
    const float* lrow = logits + (size_t)b * (Ssz * 64);

    // E = e_START; apply stored chunk operators left-to-right in f32.
    float E = (lane == START_) ? 1.0f : 0.0f;
    int Dtot = 0;
#pragma unroll 1
    for (int c = 0; c < NC; ++c) {
        if (c * CH >= len) break;          // remaining chunks are identity
        const float4* g4 =
            (const float4*)(Gws + (size_t)(b * NC + c) * 4096 + lane * 64);
        float4 gr[16];
#pragma unroll
        for (int jj = 0; jj < 16; ++jj) gr[jj] = g4[jj];

        const int Ei = __float_as_int(E);
        float En = 0.0f;
#pragma unroll
        for (int jj = 0; jj < 16; ++jj) {
            En = __builtin_fmaf(gr[jj].x,
                __int_as_float(__builtin_amdgcn_readlane(Ei, 4 * jj + 0)), En);
            En = __builtin_fmaf(gr[jj].y,
                __int_as_float(__builtin_amdgcn_readlane(Ei, 4 * jj + 1)), En);
            En = __builtin_fmaf(gr[jj].z,
                __int_as_float(__builtin_amdgcn_readlane(Ei, 4 * jj + 2)), En);
            En = __builtin_fmaf(gr[jj].w,
                __int_as_float(__builtin_amdgcn_readlane(Ei, 4 * jj + 3)), En);
        }
        Dtot += Dws[b * NC + c];

        float mxv = En;                    // renorm E to ~2^0 (exact pow2)
#pragma unroll
        for (int m = 32; m >= 1; m >>= 1) mxv = fmaxf(mxv, __shfl_xor(mxv, m, 64));
        const int ee = (__float_as_int(mxv) >> 23) & 0xff;
        const float scn = __int_as_float((254 - ee) << 23);  // 2^(127-ee)
        E = En * scn;
        Dtot += ee - 127;
    }

    const float Pend = __builtin_amdgcn_exp2f(transition[END_ * 64 + lane] * L2E);
    const float tot  = wave_sum(E * Pend);
    const float norm = LN2 * ((float)Dtot + __builtin_amdgcn_logf(tot));

    // Gold path score (exact), unchanged from the serial kernel.
    const int* lab = labels + (size_t)b * Ssz;
    float g = 0.0f;
    for (int s = lane; s < len; s += 64) {
        const int l1 = lab[s];
        const int l0 = (s == 0) ? START_ : lab[s - 1];
        g += lrow[s * 64 + l1] + transition[l1 * 64 + l0];
    }
    if (lane == 0) g += transition[END_ * 64 + lab[len - 1]];
    const float gold = wave_sum(g);

    if (lane == 0) out[b] = gold - norm;
}

extern "C" void kernel_launch(void* const* d_in, const int* in_sizes, int n_in,
                              void* d_out, int out_size, void* d_ws, size_t ws_size,
                              hipStream_t stream) {
    const float* logits     = (const float*)d_in[0];
    const float* transition = (const float*)d_in[1];
    const int*   labels     = (const int*)d_in[2];
    const int*   lens       = (const int*)d_in[3];
    float*       out        = (float*)d_out;

    const size_t gBytes = (size_t)Bsz * NC * 4096 * sizeof(float);   // 32 MiB
    const size_t need   = gBytes + (size_t)Bsz * NC * sizeof(int);
    if (d_ws != nullptr && ws_size >= need) {
        float* Gws = (float*)d_ws;
        int*   Dws = (int*)((char*)d_ws + gBytes);
        crf_chunk<<<dim3(Bsz * NC), dim3(64), 0, stream>>>(
            logits, transition, lens, Gws, Dws);
        crf_combine<<<dim3(Bsz), dim3(64), 0, stream>>>(
            logits, transition, labels, lens, Gws, Dws, out);
    } else {
        crf_kernel<<<dim3(Bsz), dim3(64), 0, stream>>>(
            logits, transition, labels, lens, out);
    }
}